// Round 7
// baseline (150.591 us; speedup 1.0000x reference)
//
#include <hip/hip_runtime.h>
#include <hip/hip_bf16.h>

// B=2048, T=128, H=48, L=3. Gates G=192.
// WG = 3 waves (192 thr) x 8 batches; 256 WGs (1/CU). Weights in registers.
// Chain design: 3 barriers/step; projection done as an MFMA with Wp replicated
// across all 16 B-columns (every lane gets mean[b] in its own acc -> no
// shuffle-reduce, no cross-wave partials); L0's Whh0@h0 MFMAs hoisted before
// B3 (acc carried in registers); samples buffered in LDS (no global stores in
// loop -> no vmcnt(0) drain at barriers); v_cvt_pk_bf16_f32 for h writes.
//
// Mapping (validated rounds 1-4): A-frag lane(c,kg) = A[m=c][k=8kg..+7] per
// 32-wide ktile; B-frag = W[n][k0..k0+7], n = 48*g + 16*wv + c; D element r of
// lane(c,kg) = D[m=4kg+r][n=c], batch = m&7 = bq+r, bq = 4*(kg&1). Lane owns
// cells (j=16wv+c, b=bbase..bbase+1), bbase = 4*(kg&1)+2*(kg>>1), acc elems
// {0,1} for kg<2 else {2,3}.

using bf16x8 = __attribute__((ext_vector_type(8))) __bf16;
using u16x8  = __attribute__((ext_vector_type(8))) unsigned short;
using f32x4  = __attribute__((ext_vector_type(4))) float;

__device__ __forceinline__ float fexp2(float x){ return __builtin_amdgcn_exp2f(x); }
__device__ __forceinline__ float frcp (float x){ return __builtin_amdgcn_rcpf(x); }
__device__ __forceinline__ float sigm (float x){ return frcp(1.f + fexp2(-1.44269504f*x)); }
__device__ __forceinline__ float tanha(float x){ return 1.f - 2.f*frcp(1.f + fexp2(2.88539008f*x)); }

__device__ __forceinline__ unsigned short f2bf(float x){
  unsigned u = __float_as_uint(x);
  return (unsigned short)((u + 0x7FFFu + ((u>>16)&1u)) >> 16);  // RNE
}

__device__ __forceinline__ f32x4 mfma16(u16x8 a, u16x8 b, f32x4 c){
  return __builtin_amdgcn_mfma_f32_16x16x32_bf16(
      __builtin_bit_cast(bf16x8, a), __builtin_bit_cast(bf16x8, b), c, 0, 0, 0);
}

// LSTM cell update for this lane's two cells; returns bf16(h0) | bf16(h1)<<16.
__device__ __forceinline__ unsigned cell2(
    const f32x4& ac0, const f32x4& ac1, const f32x4& ac2, const f32x4& ac3,
    bool lo, float& cv0, float& cv1)
{
  const float gi0 = lo ? ac0[0] : ac0[2], gi1 = lo ? ac0[1] : ac0[3];
  const float gf0 = lo ? ac1[0] : ac1[2], gf1 = lo ? ac1[1] : ac1[3];
  const float gg0 = lo ? ac2[0] : ac2[2], gg1 = lo ? ac2[1] : ac2[3];
  const float go0 = lo ? ac3[0] : ac3[2], go1 = lo ? ac3[1] : ac3[3];
  const float cn0 = sigm(gf0)*cv0 + sigm(gi0)*tanha(gg0);
  const float cn1 = sigm(gf1)*cv1 + sigm(gi1)*tanha(gg1);
  cv0 = cn0; cv1 = cn1;
  const float hv0 = sigm(go0)*tanha(cn0);
  const float hv1 = sigm(go1)*tanha(cn1);
  unsigned pk;
  asm("v_cvt_pk_bf16_f32 %0, %1, %2" : "=v"(pk) : "v"(hv0), "v"(hv1));
  return pk;
}

#define MM4(A, WK) \
  ac0 = mfma16(A, WK[0], ac0); ac1 = mfma16(A, WK[1], ac1); \
  ac2 = mfma16(A, WK[2], ac2); ac3 = mfma16(A, WK[3], ac3);

__global__ __launch_bounds__(192, 1) void lstm_fused(
    const float* __restrict__ adj, const float* __restrict__ eps,
    const float* __restrict__ Wi,  const float* __restrict__ bi,
    const float* __restrict__ Wa,  const float* __restrict__ ba,
    const float* __restrict__ Wp,  const float* __restrict__ bp,
    const float* __restrict__ Wih, const float* __restrict__ Whh,
    const float* __restrict__ bih, const float* __restrict__ bhh,
    const float* __restrict__ h0,  const float* __restrict__ c0,
    float* __restrict__ out)
{
  const int tid   = threadIdx.x;
  const int wv    = tid >> 6;          // 0..2
  const int lane  = tid & 63;
  const int c     = lane & 15;
  const int kg    = lane >> 4;         // 0..3
  const int j     = 16*wv + c;         // owned hidden index
  const int b0    = blockIdx.x * 8;    // 8 batches per WG
  const int bq    = 4*(kg & 1);        // acc element r -> batch bq+r
  const int bbase = bq + 2*(kg >> 1);  // owned batch pair
  const bool lo   = (kg < 2);          // owned acc elements {0,1} vs {2,3}

  __shared__ __align__(16) unsigned short hbuf[3][8][104]; // h per layer; [48..63]=0 pad
  __shared__ __align__(16) float adjT[128][8];
  __shared__ __align__(16) float epsT[128][8];
  __shared__ __align__(16) float outb[128][8];             // samples, stored at end

  // ---- weight fragments -> registers ----
  u16x8 wf1[3][4], wf2[3][4];  // layers 1,2: [Wih|Whh], K=96
  u16x8 wf0[2][4], wfx[2][4];  // layer 0: Whh (K=48 pad 64); Wih for u/v passes
  u16x8 wpf[2];                // Wp replicated to all 16 columns (mean-MFMA)
  float biasr1[4], biasr2[4], biasr0[4];
#pragma unroll
  for (int kk = 0; kk < 3; ++kk) {
    const int k0 = 32*kk + 8*kg;
#pragma unroll
    for (int g = 0; g < 4; ++g) {
      const int n = 48*g + j;
#pragma unroll
      for (int l = 1; l < 3; ++l) {
        const float* src = (k0 < 48) ? (Wih + ((l*192 + n)*48 + k0))
                                     : (Whh + ((l*192 + n)*48 + (k0 - 48)));
        float4 p0 = *reinterpret_cast<const float4*>(src);
        float4 p1 = *reinterpret_cast<const float4*>(src + 4);
        u16x8 f;
        f[0]=f2bf(p0.x); f[1]=f2bf(p0.y); f[2]=f2bf(p0.z); f[3]=f2bf(p0.w);
        f[4]=f2bf(p1.x); f[5]=f2bf(p1.y); f[6]=f2bf(p1.z); f[7]=f2bf(p1.w);
        if (l == 1) wf1[kk][g] = f; else wf2[kk][g] = f;
      }
    }
  }
#pragma unroll
  for (int kk = 0; kk < 2; ++kk) {
    const int k0 = 32*kk + 8*kg;
#pragma unroll
    for (int g = 0; g < 4; ++g) {
      const int n = 48*g + j;
      u16x8 fh = {0,0,0,0,0,0,0,0}, fx = fh;
      if (k0 < 48) {
        const float* sh = Whh + (n*48 + k0);      // layer 0
        const float* sx = Wih + (n*48 + k0);
        float4 p0 = *reinterpret_cast<const float4*>(sh);
        float4 p1 = *reinterpret_cast<const float4*>(sh + 4);
        fh[0]=f2bf(p0.x); fh[1]=f2bf(p0.y); fh[2]=f2bf(p0.z); fh[3]=f2bf(p0.w);
        fh[4]=f2bf(p1.x); fh[5]=f2bf(p1.y); fh[6]=f2bf(p1.z); fh[7]=f2bf(p1.w);
        p0 = *reinterpret_cast<const float4*>(sx);
        p1 = *reinterpret_cast<const float4*>(sx + 4);
        fx[0]=f2bf(p0.x); fx[1]=f2bf(p0.y); fx[2]=f2bf(p0.z); fx[3]=f2bf(p0.w);
        fx[4]=f2bf(p1.x); fx[5]=f2bf(p1.y); fx[6]=f2bf(p1.z); fx[7]=f2bf(p1.w);
      }
      wf0[kk][g] = fh; wfx[kk][g] = fx;
    }
    u16x8 fp = {0,0,0,0,0,0,0,0};
#pragma unroll
    for (int e = 0; e < 8; ++e) {
      const int k = k0 + e;
      if (k < 48) fp[e] = f2bf(Wp[k]);
    }
    wpf[kk] = fp;   // same for every column c -> every lane's acc = mean
  }
#pragma unroll
  for (int g = 0; g < 4; ++g) {
    const int n = 48*g + j;
    biasr0[g] = bih[        n] + bhh[        n];
    biasr1[g] = bih[192   + n] + bhh[192   + n];
    biasr2[g] = bih[2*192 + n] + bhh[2*192 + n];
  }

  // ---- stage adj/eps transposed: [t][b] ----
  for (int i = tid; i < 256; i += 192) {
    const int b = i >> 5, q = i & 31;
    const float4 va = reinterpret_cast<const float4*>(adj + (size_t)(b0+b)*128)[q];
    adjT[4*q+0][b]=va.x; adjT[4*q+1][b]=va.y; adjT[4*q+2][b]=va.z; adjT[4*q+3][b]=va.w;
    const float4 ve = reinterpret_cast<const float4*>(eps + (size_t)(b0+b)*128)[q];
    epsT[4*q+0][b]=ve.x; epsT[4*q+1][b]=ve.y; epsT[4*q+2][b]=ve.z; epsT[4*q+3][b]=ve.w;
  }
  const float bp0 = bp[0];
  __syncthreads();

  // ---- adjemb -> A_u (hbuf[0]), A_v (hbuf[1]); zero pads ----
  for (int cid = tid; cid < 384; cid += 192) {
    const int b = cid & 7, jj = cid >> 3;
    float s = ba[jj];
    const float* wr = Wa + jj*128;
    for (int t2 = 0; t2 < 128; ++t2) s += adjT[t2][b] * wr[t2];
    hbuf[0][b][jj] = f2bf(Wi[jj] * s);
    hbuf[1][b][jj] = f2bf(bi[jj] * s);
  }
  for (int cid = tid; cid < 384; cid += 192) {   // pads j 48..63, all 3 layers
    const int l = cid / 128, r2 = cid % 128, b = r2 >> 4, jj = 48 + (r2 & 15);
    hbuf[l][b][jj] = 0;
  }
  __syncthreads();

  // ---- u,v via MFMA passes (C-layout == gate acc layout) ----
  f32x4 uu[4], vb0[4];
  {
    const f32x4 z4 = {0.f,0.f,0.f,0.f};
    const unsigned short* rp = &hbuf[0][c & 7][0];
    u16x8 A0 = *reinterpret_cast<const u16x8*>(rp + 8*kg);
    u16x8 A1 = *reinterpret_cast<const u16x8*>(rp + 32 + 8*kg);
#pragma unroll
    for (int g = 0; g < 4; ++g)
      uu[g] = mfma16(A1, wfx[1][g], mfma16(A0, wfx[0][g], z4));
    rp = &hbuf[1][c & 7][0];
    A0 = *reinterpret_cast<const u16x8*>(rp + 8*kg);
    A1 = *reinterpret_cast<const u16x8*>(rp + 32 + 8*kg);
#pragma unroll
    for (int g = 0; g < 4; ++g) {
      f32x4 v = mfma16(A1, wfx[1][g], mfma16(A0, wfx[0][g], z4));
      const f32x4 bsp = {biasr0[g], biasr0[g], biasr0[g], biasr0[g]};
      vb0[g] = v + bsp;
    }
  }
  __syncthreads();   // u/v reads done before h-init overwrites

  // ---- h/c init ----
  for (int cid = tid; cid < 1152; cid += 192) {
    const int l = cid / 384, r2 = cid % 384, b = r2 & 7, jj = r2 >> 3;
    hbuf[l][b][jj] = f2bf(h0[l*48 + jj]);
  }
  float cc00, cc01, cc10, cc11, cc20, cc21;
  cc00 = cc01 = c0[       j];
  cc10 = cc11 = c0[48   + j];
  cc20 = cc21 = c0[2*48 + j];
  __syncthreads();

  // ---- pre-loop: gacc = vb0 + Whh0 @ h0(init) ----
  f32x4 g0, g1, g2, g3;
  {
    const unsigned short* rp = &hbuf[0][c & 7][0];
    const u16x8 A0 = *reinterpret_cast<const u16x8*>(rp + 8*kg);
    const u16x8 A1 = *reinterpret_cast<const u16x8*>(rp + 32 + 8*kg);
    g0 = vb0[0]; g1 = vb0[1]; g2 = vb0[2]; g3 = vb0[3];
    g0 = mfma16(A0, wf0[0][0], g0); g1 = mfma16(A0, wf0[0][1], g1);
    g2 = mfma16(A0, wf0[0][2], g2); g3 = mfma16(A0, wf0[0][3], g3);
    g0 = mfma16(A1, wf0[1][0], g0); g1 = mfma16(A1, wf0[1][1], g1);
    g2 = mfma16(A1, wf0[1][2], g2); g3 = mfma16(A1, wf0[1][3], g3);
  }

  const f32x4 bp4 = {bp0, bp0, bp0, bp0};
  f32x4 sampv = {0.f,0.f,0.f,0.f};

  for (int t = 0; t < 128; ++t) {
    // ---- samp(t-1): MFMA mean from h2(t-1) (every lane gets its 4 batches) ----
    if (t) {
      const u16x8 mh0 = *reinterpret_cast<const u16x8*>(&hbuf[2][c & 7][8*kg]);
      const u16x8 mh1 = *reinterpret_cast<const u16x8*>(&hbuf[2][c & 7][32 + 8*kg]);
      const f32x4 ev = *reinterpret_cast<const f32x4*>(&epsT[t-1][bq]);
      const f32x4 av = *reinterpret_cast<const f32x4*>(&adjT[t-1][bq]);
      f32x4 mz = {0.f,0.f,0.f,0.f};
      mz = mfma16(mh0, wpf[0], mz);
      mz = mfma16(mh1, wpf[1], mz);
      sampv = (mz + bp4 + ev) * av;
      if (tid == 0 || tid == 16)
        *reinterpret_cast<f32x4*>(&outb[t-1][bq]) = sampv;
    }
    // ---- L0 finish: gacc += samp*u, cell, write h0(t) ----
    g0 += sampv*uu[0]; g1 += sampv*uu[1]; g2 += sampv*uu[2]; g3 += sampv*uu[3];
    {
      const unsigned pk = cell2(g0, g1, g2, g3, lo, cc00, cc01);
      hbuf[0][bbase    ][j] = (unsigned short)pk;
      hbuf[0][bbase + 1][j] = (unsigned short)(pk >> 16);
    }
    // prefetch L1 old-h part (h1(t-1); next write is after B1 -> safe)
    u16x8 a11 = {0,0,0,0,0,0,0,0}, a12;
    if (kg >= 2) a11 = *reinterpret_cast<const u16x8*>(&hbuf[1][c & 7][8*kg - 16]);
    a12 = *reinterpret_cast<const u16x8*>(&hbuf[1][c & 7][16 + 8*kg]);
    __syncthreads();   // B1: h0(t) visible
    // ---- L1 ----
    {
      const unsigned short* rp = &hbuf[0][c & 7][0];
      const u16x8 a10 = *reinterpret_cast<const u16x8*>(rp + 8*kg);
      if (kg < 2) a11 = *reinterpret_cast<const u16x8*>(rp + 32 + 8*kg);
      f32x4 ac0 = {biasr1[0], biasr1[0], biasr1[0], biasr1[0]};
      f32x4 ac1 = {biasr1[1], biasr1[1], biasr1[1], biasr1[1]};
      f32x4 ac2 = {biasr1[2], biasr1[2], biasr1[2], biasr1[2]};
      f32x4 ac3 = {biasr1[3], biasr1[3], biasr1[3], biasr1[3]};
      MM4(a12, wf1[2]);   // prefetched: issues while a10/a11 load
      MM4(a10, wf1[0]);
      MM4(a11, wf1[1]);
      const unsigned pk = cell2(ac0, ac1, ac2, ac3, lo, cc10, cc11);
      hbuf[1][bbase    ][j] = (unsigned short)pk;
      hbuf[1][bbase + 1][j] = (unsigned short)(pk >> 16);
    }
    // prefetch L2 old-h part (h2(t-1); next write is after B2 -> safe)
    u16x8 a21 = {0,0,0,0,0,0,0,0}, a22;
    if (kg >= 2) a21 = *reinterpret_cast<const u16x8*>(&hbuf[2][c & 7][8*kg - 16]);
    a22 = *reinterpret_cast<const u16x8*>(&hbuf[2][c & 7][16 + 8*kg]);
    __syncthreads();   // B2: h1(t) visible
    // ---- L2 + hoisted L0-MFMA for t+1 ----
    {
      const unsigned short* rp = &hbuf[1][c & 7][0];
      const u16x8 a20 = *reinterpret_cast<const u16x8*>(rp + 8*kg);
      if (kg < 2) a21 = *reinterpret_cast<const u16x8*>(rp + 32 + 8*kg);
      // prefetch next-step L0 A-frags (h0(t): written before B1, next write after B3)
      const unsigned short* rp0 = &hbuf[0][c & 7][0];
      const u16x8 a00 = *reinterpret_cast<const u16x8*>(rp0 + 8*kg);
      const u16x8 a01 = *reinterpret_cast<const u16x8*>(rp0 + 32 + 8*kg);
      f32x4 ac0 = {biasr2[0], biasr2[0], biasr2[0], biasr2[0]};
      f32x4 ac1 = {biasr2[1], biasr2[1], biasr2[1], biasr2[1]};
      f32x4 ac2 = {biasr2[2], biasr2[2], biasr2[2], biasr2[2]};
      f32x4 ac3 = {biasr2[3], biasr2[3], biasr2[3], biasr2[3]};
      MM4(a22, wf2[2]);   // prefetched first
      MM4(a20, wf2[0]);
      MM4(a21, wf2[1]);
      const unsigned pk = cell2(ac0, ac1, ac2, ac3, lo, cc20, cc21);
      hbuf[2][bbase    ][j] = (unsigned short)pk;
      hbuf[2][bbase + 1][j] = (unsigned short)(pk >> 16);
      // hoisted L0 gate MFMAs for step t+1 (off the post-B3 chain)
      g0 = vb0[0]; g1 = vb0[1]; g2 = vb0[2]; g3 = vb0[3];
      g0 = mfma16(a00, wf0[0][0], g0); g1 = mfma16(a00, wf0[0][1], g1);
      g2 = mfma16(a00, wf0[0][2], g2); g3 = mfma16(a00, wf0[0][3], g3);
      g0 = mfma16(a01, wf0[1][0], g0); g1 = mfma16(a01, wf0[1][1], g1);
      g2 = mfma16(a01, wf0[1][2], g2); g3 = mfma16(a01, wf0[1][3], g3);
    }
    __syncthreads();   // B3: h2(t) + h-writes settled
  }
  // ---- epilogue: samp(127) ----
  {
    const u16x8 mh0 = *reinterpret_cast<const u16x8*>(&hbuf[2][c & 7][8*kg]);
    const u16x8 mh1 = *reinterpret_cast<const u16x8*>(&hbuf[2][c & 7][32 + 8*kg]);
    const f32x4 ev = *reinterpret_cast<const f32x4*>(&epsT[127][bq]);
    const f32x4 av = *reinterpret_cast<const f32x4*>(&adjT[127][bq]);
    f32x4 mz = {0.f,0.f,0.f,0.f};
    mz = mfma16(mh0, wpf[0], mz);
    mz = mfma16(mh1, wpf[1], mz);
    const f32x4 sv = (mz + bp4 + ev) * av;
    if (tid == 0 || tid == 16)
      *reinterpret_cast<f32x4*>(&outb[127][bq]) = sv;
  }
  __syncthreads();
  // ---- final coalesced store of all samples ----
  for (int i = tid; i < 1024; i += 192) {
    const int b = i >> 7, tt = i & 127;
    out[(size_t)(b0 + b)*128 + tt] = outb[tt][b];
  }
}

extern "C" void kernel_launch(void* const* d_in, const int* in_sizes, int n_in,
                              void* d_out, int out_size, void* d_ws, size_t ws_size,
                              hipStream_t stream) {
  const float* adj = (const float*)d_in[0];
  const float* eps = (const float*)d_in[1];
  const float* Wi  = (const float*)d_in[2];
  const float* bi  = (const float*)d_in[3];
  const float* Wa  = (const float*)d_in[4];
  const float* ba  = (const float*)d_in[5];
  const float* Wp  = (const float*)d_in[6];
  const float* bp  = (const float*)d_in[7];
  const float* Wih = (const float*)d_in[8];
  const float* Whh = (const float*)d_in[9];
  const float* bih = (const float*)d_in[10];
  const float* bhh = (const float*)d_in[11];
  const float* h0  = (const float*)d_in[12];
  const float* c0  = (const float*)d_in[13];

  lstm_fused<<<dim3(2048/8), dim3(192), 0, stream>>>(
      adj, eps, Wi, bi, Wa, ba, Wp, bp, Wih, Whh, bih, bhh, h0, c0, (float*)d_out);
}

// Round 8
// 150.032 us; speedup vs baseline: 1.0037x; 1.0037x over previous
//
#include <hip/hip_runtime.h>
#include <hip/hip_bf16.h>

// B=2048, T=128, H=48, L=3. Gates G=192.
// WG = 3 waves (192 thr) x 8 batches; 256 WGs (1/CU). Weights in registers.
// Chain design: 3 barriers/step; projection done as an MFMA with Wp replicated
// across all 16 B-columns (every lane gets mean[b] in its own acc -> no
// shuffle-reduce, no cross-wave partials); L0's Whh0@h0 MFMAs hoisted before
// B3 (acc carried in registers); samples buffered in LDS (no global stores in
// loop -> no vmcnt(0) drain at barriers); v_cvt_pk_bf16_f32 for h writes.
//
// Mapping (validated rounds 1-4): A-frag lane(c,kg) = A[m=c][k=8kg..+7] per
// 32-wide ktile; B-frag = W[n][k0..k0+7], n = 48*g + 16*wv + c; D element r of
// lane(c,kg) = D[m=4kg+r][n=c], batch = m&7 = bq+r, bq = 4*(kg&1). Lane owns
// cells (j=16wv+c, b=bbase..bbase+1), bbase = 4*(kg&1)+2*(kg>>1), acc elems
// {0,1} for kg<2 else {2,3}.

using bf16x8 = __attribute__((ext_vector_type(8))) __bf16;
using u16x8  = __attribute__((ext_vector_type(8))) unsigned short;
using f32x4  = __attribute__((ext_vector_type(4))) float;

__device__ __forceinline__ float fexp2(float x){ return __builtin_amdgcn_exp2f(x); }
__device__ __forceinline__ float frcp (float x){ return __builtin_amdgcn_rcpf(x); }
__device__ __forceinline__ float sigm (float x){ return frcp(1.f + fexp2(-1.44269504f*x)); }
__device__ __forceinline__ float tanha(float x){ return 1.f - 2.f*frcp(1.f + fexp2(2.88539008f*x)); }

__device__ __forceinline__ unsigned short f2bf(float x){
  unsigned u = __float_as_uint(x);
  return (unsigned short)((u + 0x7FFFu + ((u>>16)&1u)) >> 16);  // RNE
}

__device__ __forceinline__ f32x4 mfma16(u16x8 a, u16x8 b, f32x4 c){
  return __builtin_amdgcn_mfma_f32_16x16x32_bf16(
      __builtin_bit_cast(bf16x8, a), __builtin_bit_cast(bf16x8, b), c, 0, 0, 0);
}

// LSTM cell update for this lane's two cells; returns bf16(h0) | bf16(h1)<<16.
__device__ __forceinline__ unsigned cell2(
    const f32x4& ac0, const f32x4& ac1, const f32x4& ac2, const f32x4& ac3,
    bool lo, float& cv0, float& cv1)
{
  const float gi0 = lo ? ac0[0] : ac0[2], gi1 = lo ? ac0[1] : ac0[3];
  const float gf0 = lo ? ac1[0] : ac1[2], gf1 = lo ? ac1[1] : ac1[3];
  const float gg0 = lo ? ac2[0] : ac2[2], gg1 = lo ? ac2[1] : ac2[3];
  const float go0 = lo ? ac3[0] : ac3[2], go1 = lo ? ac3[1] : ac3[3];
  const float cn0 = sigm(gf0)*cv0 + sigm(gi0)*tanha(gg0);
  const float cn1 = sigm(gf1)*cv1 + sigm(gi1)*tanha(gg1);
  cv0 = cn0; cv1 = cn1;
  const float hv0 = sigm(go0)*tanha(cn0);
  const float hv1 = sigm(go1)*tanha(cn1);
  unsigned pk;
  asm("v_cvt_pk_bf16_f32 %0, %1, %2" : "=v"(pk) : "v"(hv0), "v"(hv1));
  return pk;
}

#define MM4(A, WK) \
  ac0 = mfma16(A, WK[0], ac0); ac1 = mfma16(A, WK[1], ac1); \
  ac2 = mfma16(A, WK[2], ac2); ac3 = mfma16(A, WK[3], ac3);

__global__ __launch_bounds__(192, 1) void lstm_fused(
    const float* __restrict__ adj, const float* __restrict__ eps,
    const float* __restrict__ Wi,  const float* __restrict__ bi,
    const float* __restrict__ Wa,  const float* __restrict__ ba,
    const float* __restrict__ Wp,  const float* __restrict__ bp,
    const float* __restrict__ Wih, const float* __restrict__ Whh,
    const float* __restrict__ bih, const float* __restrict__ bhh,
    const float* __restrict__ h0,  const float* __restrict__ c0,
    float* __restrict__ out)
{
  const int tid   = threadIdx.x;
  const int wv    = tid >> 6;          // 0..2
  const int lane  = tid & 63;
  const int c     = lane & 15;
  const int kg    = lane >> 4;         // 0..3
  const int j     = 16*wv + c;         // owned hidden index
  const int b0    = blockIdx.x * 8;    // 8 batches per WG
  const int bq    = 4*(kg & 1);        // acc element r -> batch bq+r
  const int bbase = bq + 2*(kg >> 1);  // owned batch pair
  const bool lo   = (kg < 2);          // owned acc elements {0,1} vs {2,3}

  __shared__ __align__(16) unsigned short hbuf[3][8][104]; // h per layer; [48..63]=0 pad
  __shared__ __align__(16) float adjT[128][8];
  __shared__ __align__(16) float epsT[128][8];
  __shared__ __align__(16) float outb[128][8];             // samples, stored at end

  // ---- weight fragments -> registers ----
  u16x8 wf1[3][4], wf2[3][4];  // layers 1,2: [Wih|Whh], K=96
  u16x8 wf0[2][4], wfx[2][4];  // layer 0: Whh (K=48 pad 64); Wih for u/v passes
  u16x8 wpf[2];                // Wp replicated to all 16 columns (mean-MFMA)
  float biasr1[4], biasr2[4], biasr0[4];
#pragma unroll
  for (int kk = 0; kk < 3; ++kk) {
    const int k0 = 32*kk + 8*kg;
#pragma unroll
    for (int g = 0; g < 4; ++g) {
      const int n = 48*g + j;
#pragma unroll
      for (int l = 1; l < 3; ++l) {
        const float* src = (k0 < 48) ? (Wih + ((l*192 + n)*48 + k0))
                                     : (Whh + ((l*192 + n)*48 + (k0 - 48)));
        float4 p0 = *reinterpret_cast<const float4*>(src);
        float4 p1 = *reinterpret_cast<const float4*>(src + 4);
        u16x8 f;
        f[0]=f2bf(p0.x); f[1]=f2bf(p0.y); f[2]=f2bf(p0.z); f[3]=f2bf(p0.w);
        f[4]=f2bf(p1.x); f[5]=f2bf(p1.y); f[6]=f2bf(p1.z); f[7]=f2bf(p1.w);
        if (l == 1) wf1[kk][g] = f; else wf2[kk][g] = f;
      }
    }
  }
#pragma unroll
  for (int kk = 0; kk < 2; ++kk) {
    const int k0 = 32*kk + 8*kg;
#pragma unroll
    for (int g = 0; g < 4; ++g) {
      const int n = 48*g + j;
      u16x8 fh = {0,0,0,0,0,0,0,0}, fx = fh;
      if (k0 < 48) {
        const float* sh = Whh + (n*48 + k0);      // layer 0
        const float* sx = Wih + (n*48 + k0);
        float4 p0 = *reinterpret_cast<const float4*>(sh);
        float4 p1 = *reinterpret_cast<const float4*>(sh + 4);
        fh[0]=f2bf(p0.x); fh[1]=f2bf(p0.y); fh[2]=f2bf(p0.z); fh[3]=f2bf(p0.w);
        fh[4]=f2bf(p1.x); fh[5]=f2bf(p1.y); fh[6]=f2bf(p1.z); fh[7]=f2bf(p1.w);
        p0 = *reinterpret_cast<const float4*>(sx);
        p1 = *reinterpret_cast<const float4*>(sx + 4);
        fx[0]=f2bf(p0.x); fx[1]=f2bf(p0.y); fx[2]=f2bf(p0.z); fx[3]=f2bf(p0.w);
        fx[4]=f2bf(p1.x); fx[5]=f2bf(p1.y); fx[6]=f2bf(p1.z); fx[7]=f2bf(p1.w);
      }
      wf0[kk][g] = fh; wfx[kk][g] = fx;
    }
    u16x8 fp = {0,0,0,0,0,0,0,0};
#pragma unroll
    for (int e = 0; e < 8; ++e) {
      const int k = k0 + e;
      if (k < 48) fp[e] = f2bf(Wp[k]);
    }
    wpf[kk] = fp;   // same for every column c -> every lane's acc = mean
  }
#pragma unroll
  for (int g = 0; g < 4; ++g) {
    const int n = 48*g + j;
    biasr0[g] = bih[        n] + bhh[        n];
    biasr1[g] = bih[192   + n] + bhh[192   + n];
    biasr2[g] = bih[2*192 + n] + bhh[2*192 + n];
  }

  // ---- stage adj/eps transposed: [t][b] ----
  for (int i = tid; i < 256; i += 192) {
    const int b = i >> 5, q = i & 31;
    const float4 va = reinterpret_cast<const float4*>(adj + (size_t)(b0+b)*128)[q];
    adjT[4*q+0][b]=va.x; adjT[4*q+1][b]=va.y; adjT[4*q+2][b]=va.z; adjT[4*q+3][b]=va.w;
    const float4 ve = reinterpret_cast<const float4*>(eps + (size_t)(b0+b)*128)[q];
    epsT[4*q+0][b]=ve.x; epsT[4*q+1][b]=ve.y; epsT[4*q+2][b]=ve.z; epsT[4*q+3][b]=ve.w;
  }
  const float bp0 = bp[0];
  __syncthreads();

  // ---- adjemb -> A_u (hbuf[0]), A_v (hbuf[1]); zero pads ----
  for (int cid = tid; cid < 384; cid += 192) {
    const int b = cid & 7, jj = cid >> 3;
    float s = ba[jj];
    const float* wr = Wa + jj*128;
    for (int t2 = 0; t2 < 128; ++t2) s += adjT[t2][b] * wr[t2];
    hbuf[0][b][jj] = f2bf(Wi[jj] * s);
    hbuf[1][b][jj] = f2bf(bi[jj] * s);
  }
  for (int cid = tid; cid < 384; cid += 192) {   // pads j 48..63, all 3 layers
    const int l = cid / 128, r2 = cid % 128, b = r2 >> 4, jj = 48 + (r2 & 15);
    hbuf[l][b][jj] = 0;
  }
  __syncthreads();

  // ---- u,v via MFMA passes (C-layout == gate acc layout) ----
  f32x4 uu[4], vb0[4];
  {
    const f32x4 z4 = {0.f,0.f,0.f,0.f};
    const unsigned short* rp = &hbuf[0][c & 7][0];
    u16x8 A0 = *reinterpret_cast<const u16x8*>(rp + 8*kg);
    u16x8 A1 = *reinterpret_cast<const u16x8*>(rp + 32 + 8*kg);
#pragma unroll
    for (int g = 0; g < 4; ++g)
      uu[g] = mfma16(A1, wfx[1][g], mfma16(A0, wfx[0][g], z4));
    rp = &hbuf[1][c & 7][0];
    A0 = *reinterpret_cast<const u16x8*>(rp + 8*kg);
    A1 = *reinterpret_cast<const u16x8*>(rp + 32 + 8*kg);
#pragma unroll
    for (int g = 0; g < 4; ++g) {
      f32x4 v = mfma16(A1, wfx[1][g], mfma16(A0, wfx[0][g], z4));
      const f32x4 bsp = {biasr0[g], biasr0[g], biasr0[g], biasr0[g]};
      vb0[g] = v + bsp;
    }
  }
  __syncthreads();   // u/v reads done before h-init overwrites

  // ---- h/c init ----
  for (int cid = tid; cid < 1152; cid += 192) {
    const int l = cid / 384, r2 = cid % 384, b = r2 & 7, jj = r2 >> 3;
    hbuf[l][b][jj] = f2bf(h0[l*48 + jj]);
  }
  float cc00, cc01, cc10, cc11, cc20, cc21;
  cc00 = cc01 = c0[       j];
  cc10 = cc11 = c0[48   + j];
  cc20 = cc21 = c0[2*48 + j];
  __syncthreads();

  // ---- pre-loop: gacc = vb0 + Whh0 @ h0(init) ----
  f32x4 g0, g1, g2, g3;
  {
    const unsigned short* rp = &hbuf[0][c & 7][0];
    const u16x8 A0 = *reinterpret_cast<const u16x8*>(rp + 8*kg);
    const u16x8 A1 = *reinterpret_cast<const u16x8*>(rp + 32 + 8*kg);
    g0 = vb0[0]; g1 = vb0[1]; g2 = vb0[2]; g3 = vb0[3];
    g0 = mfma16(A0, wf0[0][0], g0); g1 = mfma16(A0, wf0[0][1], g1);
    g2 = mfma16(A0, wf0[0][2], g2); g3 = mfma16(A0, wf0[0][3], g3);
    g0 = mfma16(A1, wf0[1][0], g0); g1 = mfma16(A1, wf0[1][1], g1);
    g2 = mfma16(A1, wf0[1][2], g2); g3 = mfma16(A1, wf0[1][3], g3);
  }

  const f32x4 bp4 = {bp0, bp0, bp0, bp0};
  f32x4 sampv = {0.f,0.f,0.f,0.f};

  for (int t = 0; t < 128; ++t) {
    // ---- samp(t-1): MFMA mean from h2(t-1) (every lane gets its 4 batches) ----
    if (t) {
      const u16x8 mh0 = *reinterpret_cast<const u16x8*>(&hbuf[2][c & 7][8*kg]);
      const u16x8 mh1 = *reinterpret_cast<const u16x8*>(&hbuf[2][c & 7][32 + 8*kg]);
      const f32x4 ev = *reinterpret_cast<const f32x4*>(&epsT[t-1][bq]);
      const f32x4 av = *reinterpret_cast<const f32x4*>(&adjT[t-1][bq]);
      f32x4 mz = {0.f,0.f,0.f,0.f};
      mz = mfma16(mh0, wpf[0], mz);
      mz = mfma16(mh1, wpf[1], mz);
      sampv = (mz + bp4 + ev) * av;
      if (tid == 0 || tid == 16)
        *reinterpret_cast<f32x4*>(&outb[t-1][bq]) = sampv;
    }
    // ---- L0 finish: gacc += samp*u, cell, write h0(t) ----
    g0 += sampv*uu[0]; g1 += sampv*uu[1]; g2 += sampv*uu[2]; g3 += sampv*uu[3];
    {
      const unsigned pk = cell2(g0, g1, g2, g3, lo, cc00, cc01);
      hbuf[0][bbase    ][j] = (unsigned short)pk;
      hbuf[0][bbase + 1][j] = (unsigned short)(pk >> 16);
    }
    // prefetch L1 old-h part (h1(t-1); next write is after B1 -> safe)
    u16x8 a11 = {0,0,0,0,0,0,0,0}, a12;
    if (kg >= 2) a11 = *reinterpret_cast<const u16x8*>(&hbuf[1][c & 7][8*kg - 16]);
    a12 = *reinterpret_cast<const u16x8*>(&hbuf[1][c & 7][16 + 8*kg]);
    __syncthreads();   // B1: h0(t) visible
    // ---- L1 ----
    {
      const unsigned short* rp = &hbuf[0][c & 7][0];
      const u16x8 a10 = *reinterpret_cast<const u16x8*>(rp + 8*kg);
      if (kg < 2) a11 = *reinterpret_cast<const u16x8*>(rp + 32 + 8*kg);
      f32x4 ac0 = {biasr1[0], biasr1[0], biasr1[0], biasr1[0]};
      f32x4 ac1 = {biasr1[1], biasr1[1], biasr1[1], biasr1[1]};
      f32x4 ac2 = {biasr1[2], biasr1[2], biasr1[2], biasr1[2]};
      f32x4 ac3 = {biasr1[3], biasr1[3], biasr1[3], biasr1[3]};
      MM4(a12, wf1[2]);   // prefetched: issues while a10/a11 load
      MM4(a10, wf1[0]);
      MM4(a11, wf1[1]);
      const unsigned pk = cell2(ac0, ac1, ac2, ac3, lo, cc10, cc11);
      hbuf[1][bbase    ][j] = (unsigned short)pk;
      hbuf[1][bbase + 1][j] = (unsigned short)(pk >> 16);
    }
    // prefetch L2 old-h part (h2(t-1); next write is after B2 -> safe)
    u16x8 a21 = {0,0,0,0,0,0,0,0}, a22;
    if (kg >= 2) a21 = *reinterpret_cast<const u16x8*>(&hbuf[2][c & 7][8*kg - 16]);
    a22 = *reinterpret_cast<const u16x8*>(&hbuf[2][c & 7][16 + 8*kg]);
    __syncthreads();   // B2: h1(t) visible
    // ---- L2 + hoisted L0-MFMA for t+1 ----
    {
      const unsigned short* rp = &hbuf[1][c & 7][0];
      const u16x8 a20 = *reinterpret_cast<const u16x8*>(rp + 8*kg);
      if (kg < 2) a21 = *reinterpret_cast<const u16x8*>(rp + 32 + 8*kg);
      // prefetch next-step L0 A-frags (h0(t): written before B1, next write after B3)
      const unsigned short* rp0 = &hbuf[0][c & 7][0];
      const u16x8 a00 = *reinterpret_cast<const u16x8*>(rp0 + 8*kg);
      const u16x8 a01 = *reinterpret_cast<const u16x8*>(rp0 + 32 + 8*kg);
      f32x4 ac0 = {biasr2[0], biasr2[0], biasr2[0], biasr2[0]};
      f32x4 ac1 = {biasr2[1], biasr2[1], biasr2[1], biasr2[1]};
      f32x4 ac2 = {biasr2[2], biasr2[2], biasr2[2], biasr2[2]};
      f32x4 ac3 = {biasr2[3], biasr2[3], biasr2[3], biasr2[3]};
      MM4(a22, wf2[2]);   // prefetched first
      MM4(a20, wf2[0]);
      MM4(a21, wf2[1]);
      const unsigned pk = cell2(ac0, ac1, ac2, ac3, lo, cc20, cc21);
      hbuf[2][bbase    ][j] = (unsigned short)pk;
      hbuf[2][bbase + 1][j] = (unsigned short)(pk >> 16);
      // hoisted L0 gate MFMAs for step t+1 (off the post-B3 chain)
      g0 = vb0[0]; g1 = vb0[1]; g2 = vb0[2]; g3 = vb0[3];
      g0 = mfma16(a00, wf0[0][0], g0); g1 = mfma16(a00, wf0[0][1], g1);
      g2 = mfma16(a00, wf0[0][2], g2); g3 = mfma16(a00, wf0[0][3], g3);
      g0 = mfma16(a01, wf0[1][0], g0); g1 = mfma16(a01, wf0[1][1], g1);
      g2 = mfma16(a01, wf0[1][2], g2); g3 = mfma16(a01, wf0[1][3], g3);
    }
    __syncthreads();   // B3: h2(t) + h-writes settled
  }
  // ---- epilogue: samp(127) ----
  {
    const u16x8 mh0 = *reinterpret_cast<const u16x8*>(&hbuf[2][c & 7][8*kg]);
    const u16x8 mh1 = *reinterpret_cast<const u16x8*>(&hbuf[2][c & 7][32 + 8*kg]);
    const f32x4 ev = *reinterpret_cast<const f32x4*>(&epsT[127][bq]);
    const f32x4 av = *reinterpret_cast<const f32x4*>(&adjT[127][bq]);
    f32x4 mz = {0.f,0.f,0.f,0.f};
    mz = mfma16(mh0, wpf[0], mz);
    mz = mfma16(mh1, wpf[1], mz);
    const f32x4 sv = (mz + bp4 + ev) * av;
    if (tid == 0 || tid == 16)
      *reinterpret_cast<f32x4*>(&outb[127][bq]) = sv;
  }
  __syncthreads();
  // ---- final coalesced store of all samples ----
  for (int i = tid; i < 1024; i += 192) {
    const int b = i >> 7, tt = i & 127;
    out[(size_t)(b0 + b)*128 + tt] = outb[tt][b];
  }
}

extern "C" void kernel_launch(void* const* d_in, const int* in_sizes, int n_in,
                              void* d_out, int out_size, void* d_ws, size_t ws_size,
                              hipStream_t stream) {
  const float* adj = (const float*)d_in[0];
  const float* eps = (const float*)d_in[1];
  const float* Wi  = (const float*)d_in[2];
  const float* bi  = (const float*)d_in[3];
  const float* Wa  = (const float*)d_in[4];
  const float* ba  = (const float*)d_in[5];
  const float* Wp  = (const float*)d_in[6];
  const float* bp  = (const float*)d_in[7];
  const float* Wih = (const float*)d_in[8];
  const float* Whh = (const float*)d_in[9];
  const float* bih = (const float*)d_in[10];
  const float* bhh = (const float*)d_in[11];
  const float* h0  = (const float*)d_in[12];
  const float* c0  = (const float*)d_in[13];

  lstm_fused<<<dim3(2048/8), dim3(192), 0, stream>>>(
      adj, eps, Wi, bi, Wa, ba, Wp, bp, Wih, Whh, bih, bhh, h0, c0, (float*)d_out);
}